// Round 5
// baseline (59.968 us; speedup 1.0000x reference)
//
#include <hip/hip_runtime.h>
#include <hip/hip_bf16.h>

// B=32, S=1024, D=768, HD=64 single-head attention, scores scaled 1/D.
// Inputs fp32, output fp32 [B,S,HD].
// Pipeline: (0) W -> bf16 transposed, (1) QKV proj via bf16 MFMA, depth-2
// register prefetch (Q pre-scaled by 1/768*log2e, V stored transposed
// [B][H][S]), (2) flash attention with 32x32 swapped-QK^T, max-free exp2
// softmax (scores O(0.05) by construction), 4-way key-split + sum-merge.

constexpr int NB = 32;
constexpr int NS = 1024;
constexpr int ND = 768;
constexpr int NH = 64;
constexpr float SC2 = (1.0f / 768.0f) * 1.4426950408889634f;

typedef __attribute__((ext_vector_type(8))) short bf16x8;
typedef __attribute__((ext_vector_type(4))) float f32x4;
typedef __attribute__((ext_vector_type(16))) float f32x16;
typedef __attribute__((ext_vector_type(4))) unsigned int u32x4;

__device__ __forceinline__ unsigned short f2bf(float f) {
    unsigned int u = __float_as_uint(f);
    u += 0x7FFFu + ((u >> 16) & 1u);   // RNE
    return (unsigned short)(u >> 16);
}

__device__ __forceinline__ unsigned int pkbf(float lo, float hi) {
    __hip_bfloat162 h = __float22bfloat162_rn(float2{lo, hi});
    return *reinterpret_cast<unsigned int*>(&h);
}

__device__ __forceinline__ void pl32swap(unsigned int a, unsigned int b,
                                         unsigned int& x, unsigned int& y) {
    auto r = __builtin_amdgcn_permlane32_swap((int)a, (int)b, false, false);
    x = (unsigned int)r[0];
    y = (unsigned int)r[1];
}

__device__ __forceinline__ float xswap_add(float v) {
    unsigned int a, b;
    pl32swap(__float_as_uint(v), __float_as_uint(v), a, b);
    return __uint_as_float(a) + __uint_as_float(b);
}

// ---------------- Kernel 0: W[768][64] x3 -> Wt[192][768] bf16 (transposed) ----
__global__ void wtrans_kernel(const float* __restrict__ Wq, const float* __restrict__ Wk,
                              const float* __restrict__ Wv, short* __restrict__ Wt) {
    int idx = blockIdx.x * 256 + threadIdx.x;      // 192*768 = 576*256
    int n = idx / ND;
    int k = idx - n * ND;
    const float* W = (n < 64) ? Wq : ((n < 128) ? Wk : Wv);
    int col = n & 63;
    Wt[idx] = (short)f2bf(W[(size_t)k * NH + col]);
}

// ---------------- Kernel 1: QKV projection -----------------------------------
// Block tile: 64 M x 192 N, K-step 64. 4 waves 2x2 (wave tile 32x96).
// Depth-2 register prefetch (named sets A/B, static indexing only).
__global__ __launch_bounds__(256) void qkv_kernel(
    const float* __restrict__ x, const short* __restrict__ Wt,
    const float* __restrict__ bq, const float* __restrict__ bk, const float* __restrict__ bv,
    short* __restrict__ Qw, short* __restrict__ Kw, short* __restrict__ Vwt)
{
    __shared__ __align__(16) short As[64][72];
    __shared__ __align__(16) short Bs[192][72];

    const int t = threadIdx.x;
    const int w = t >> 6, lane = t & 63, ln = lane & 15, g = lane >> 4;
    const int wm = w >> 1, wn = w & 1;
    const int m0 = blockIdx.x * 64;

    f32x4 acc[2][6];
    #pragma unroll
    for (int i = 0; i < 2; i++)
        #pragma unroll
        for (int j = 0; j < 6; j++) acc[i][j] = f32x4{0.f, 0.f, 0.f, 0.f};

    const int arow = t >> 2, ac0 = (t & 3) * 16;
    const float* xr0 = x + (size_t)(m0 + arow) * ND + ac0;

    float4 xpA[4], xpB[4];
    bf16x8 wpA[6], wpB[6];

    auto loadX = [&](float4 (&xp)[4], int k0) {
        #pragma unroll
        for (int q4 = 0; q4 < 4; q4++) xp[q4] = *(const float4*)(xr0 + k0 + q4 * 4);
    };
    auto loadW = [&](bf16x8 (&wp)[6], int k0) {
        #pragma unroll
        for (int it = 0; it < 3; it++) {
            int i = t + it * 256, n = i >> 2, qq = i & 3;
            const short* src = Wt + (size_t)n * ND + k0 + qq * 16;
            wp[it * 2]     = *(const bf16x8*)src;
            wp[it * 2 + 1] = *(const bf16x8*)(src + 8);
        }
    };
    auto writeLDS = [&](const float4 (&xp)[4], const bf16x8 (&wp)[6]) {
        unsigned int u[8];
        #pragma unroll
        for (int q4 = 0; q4 < 4; q4++) {
            u[q4 * 2]     = pkbf(xp[q4].x, xp[q4].y);
            u[q4 * 2 + 1] = pkbf(xp[q4].z, xp[q4].w);
        }
        *(u32x4*)&As[arow][ac0]     = u32x4{u[0], u[1], u[2], u[3]};
        *(u32x4*)&As[arow][ac0 + 8] = u32x4{u[4], u[5], u[6], u[7]};
        #pragma unroll
        for (int it = 0; it < 3; it++) {
            int i = t + it * 256, n = i >> 2, qq = i & 3;
            *(bf16x8*)&Bs[n][qq * 16]     = wp[it * 2];
            *(bf16x8*)&Bs[n][qq * 16 + 8] = wp[it * 2 + 1];
        }
    };
    auto compute = [&]() {
        bf16x8 af[2][2], bfg[2][6];
        #pragma unroll
        for (int ks = 0; ks < 2; ks++)
            #pragma unroll
            for (int mf = 0; mf < 2; mf++)
                af[ks][mf] = *(const bf16x8*)&As[wm * 32 + mf * 16 + ln][ks * 32 + g * 8];
        #pragma unroll
        for (int ks = 0; ks < 2; ks++)
            #pragma unroll
            for (int nf = 0; nf < 6; nf++)
                bfg[ks][nf] = *(const bf16x8*)&Bs[wn * 96 + nf * 16 + ln][ks * 32 + g * 8];
        __builtin_amdgcn_s_setprio(1);
        #pragma unroll
        for (int ks = 0; ks < 2; ks++)
            #pragma unroll
            for (int mf = 0; mf < 2; mf++)
                #pragma unroll
                for (int nf = 0; nf < 6; nf++)
                    acc[mf][nf] = __builtin_amdgcn_mfma_f32_16x16x32_bf16(
                        af[ks][mf], bfg[ks][nf], acc[mf][nf], 0, 0, 0);
        __builtin_amdgcn_s_setprio(0);
    };

    loadX(xpA, 0);   loadW(wpA, 0);
    loadX(xpB, 64);  loadW(wpB, 64);

    #pragma unroll 1
    for (int kt = 0; kt < 12; kt += 2) {
        // even step (reg set A)
        __syncthreads();
        writeLDS(xpA, wpA);
        __syncthreads();
        if (kt + 2 < 12) { loadX(xpA, (kt + 2) * 64); loadW(wpA, (kt + 2) * 64); }
        compute();
        // odd step (reg set B)
        __syncthreads();
        writeLDS(xpB, wpB);
        __syncthreads();
        if (kt + 3 < 12) { loadX(xpB, (kt + 3) * 64); loadW(wpB, (kt + 3) * 64); }
        compute();
    }

    #pragma unroll
    for (int nf = 0; nf < 6; nf++) {
        int n = wn * 96 + nf * 16 + ln;
        int mat = n >> 6, col = n & 63;
        const float* bp = (mat == 0) ? bq : ((mat == 1) ? bk : bv);
        float bias = bp[col];
        #pragma unroll
        for (int mf = 0; mf < 2; mf++) {
            int rbase = m0 + wm * 32 + mf * 16 + g * 4;
            #pragma unroll
            for (int r = 0; r < 4; r++) {
                float v = acc[mf][nf][r] + bias;
                int row = rbase + r;
                if (mat == 0) {
                    Qw[(size_t)row * NH + col] = (short)f2bf(v * SC2);
                } else if (mat == 1) {
                    Kw[(size_t)row * NH + col] = (short)f2bf(v);
                } else {
                    int bb = row >> 10, ss = row & 1023;
                    Vwt[((size_t)bb * NH + col) * NS + ss] = (short)f2bf(v);
                }
            }
        }
    }
}

// ---------------- Kernel 2: flash attention (32x32 swapped QK^T) -------------
// Grid: (16 q-tiles, 32 batches), 512 threads = 8 waves = 4 key-groups x 2 q-waves.
__global__ __launch_bounds__(512, 4) void attn_kernel(
    const short* __restrict__ Qw, const short* __restrict__ Kw,
    const short* __restrict__ Vwt, float* __restrict__ out)
{
    __shared__ __align__(16) short sm[4][2][64][72];  // [gk][0]=K, [gk][1]=V

    const int t = threadIdx.x;
    const int w = t >> 6;
    const int lane = t & 63, l31 = lane & 31, h32 = lane >> 5;
    const int gk = w >> 1, wq = w & 1;
    const int b = blockIdx.y, qt = blockIdx.x;

    short (*Ks)[72] = sm[gk][0];
    short (*Vs)[72] = sm[gk][1];

    const short* qbase = Qw + ((size_t)(b * NS + qt * 64 + wq * 32 + l31)) * NH + h32 * 8;
    bf16x8 qf[4];
    #pragma unroll
    for (int ks = 0; ks < 4; ks++) qf[ks] = *(const bf16x8*)(qbase + ks * 16);

    f32x16 oacc[2];
    #pragma unroll
    for (int i = 0; i < 16; i++) { oacc[0][i] = 0.f; oacc[1][i] = 0.f; }
    float l_part = 0.f;

    const int tg = t & 127;
    const int srow = tg >> 1, scb = (tg & 1) * 32;
    const int key00 = gk * 256;
    const short* ksrc = Kw + ((size_t)(b * NS + key00 + srow)) * NH + scb;
    const short* vsrc = Vwt + ((size_t)(b * NH + srow)) * NS + key00 + scb;

    bf16x8 kpre[4], vpre[4];
    #pragma unroll
    for (int i = 0; i < 4; i++) {
        kpre[i] = *(const bf16x8*)(ksrc + i * 8);
        vpre[i] = *(const bf16x8*)(vsrc + i * 8);
    }
    #pragma unroll
    for (int i = 0; i < 4; i++) {
        *(bf16x8*)&Ks[srow][scb + i * 8] = kpre[i];
        *(bf16x8*)&Vs[srow][scb + i * 8] = vpre[i];
    }
    __syncthreads();

    constexpr int NT = 4;
    for (int kt = 0; kt < NT; kt++) {
        if (kt < NT - 1) {
            const short* kp = ksrc + (size_t)(kt + 1) * 64 * NH;
            const short* vp = vsrc + (kt + 1) * 64;
            #pragma unroll
            for (int i = 0; i < 4; i++) {
                kpre[i] = *(const bf16x8*)(kp + i * 8);
                vpre[i] = *(const bf16x8*)(vp + i * 8);
            }
        }

        float sl = 0.f;
        u32x4 pw[4];

        // ---- keys [0,32): S^T = K*Q^T, exp2, pack -> pw[0..1]
        {
            f32x16 st;
            #pragma unroll
            for (int i = 0; i < 16; i++) st[i] = 0.f;
            __builtin_amdgcn_s_setprio(1);
            #pragma unroll
            for (int ks = 0; ks < 4; ks++) {
                bf16x8 a0 = *(const bf16x8*)&Ks[l31][ks * 16 + h32 * 8];
                st = __builtin_amdgcn_mfma_f32_32x32x16_bf16(a0, qf[ks], st, 0, 0, 0);
            }
            __builtin_amdgcn_s_setprio(0);
            #pragma unroll
            for (int i = 0; i < 16; i++) { st[i] = exp2f(st[i]); sl += st[i]; }
            unsigned int c[8];
            #pragma unroll
            for (int i = 0; i < 8; i++) c[i] = pkbf(st[2 * i], st[2 * i + 1]);
            unsigned int w0, w1, w2, w3;
            pl32swap(c[0], c[2], w0, w2); pl32swap(c[1], c[3], w1, w3);
            pw[0] = u32x4{w0, w1, w2, w3};
            pl32swap(c[4], c[6], w0, w2); pl32swap(c[5], c[7], w1, w3);
            pw[1] = u32x4{w0, w1, w2, w3};
        }
        // ---- keys [32,64)
        {
            f32x16 st;
            #pragma unroll
            for (int i = 0; i < 16; i++) st[i] = 0.f;
            __builtin_amdgcn_s_setprio(1);
            #pragma unroll
            for (int ks = 0; ks < 4; ks++) {
                bf16x8 a1 = *(const bf16x8*)&Ks[32 + l31][ks * 16 + h32 * 8];
                st = __builtin_amdgcn_mfma_f32_32x32x16_bf16(a1, qf[ks], st, 0, 0, 0);
            }
            __builtin_amdgcn_s_setprio(0);
            #pragma unroll
            for (int i = 0; i < 16; i++) { st[i] = exp2f(st[i]); sl += st[i]; }
            unsigned int c[8];
            #pragma unroll
            for (int i = 0; i < 8; i++) c[i] = pkbf(st[2 * i], st[2 * i + 1]);
            unsigned int w0, w1, w2, w3;
            pl32swap(c[0], c[2], w0, w2); pl32swap(c[1], c[3], w1, w3);
            pw[2] = u32x4{w0, w1, w2, w3};
            pl32swap(c[4], c[6], w0, w2); pl32swap(c[5], c[7], w1, w3);
            pw[3] = u32x4{w0, w1, w2, w3};
        }
        l_part += sl;

        // ---- O^T += V^T * P^T
        __builtin_amdgcn_s_setprio(1);
        #pragma unroll
        for (int ks = 0; ks < 4; ks++) {
            bf16x8 pb = *(bf16x8*)&pw[ks];
            #pragma unroll
            for (int ht = 0; ht < 2; ht++) {
                bf16x8 va = *(const bf16x8*)&Vs[ht * 32 + l31][ks * 16 + h32 * 8];
                oacc[ht] = __builtin_amdgcn_mfma_f32_32x32x16_bf16(va, pb, oacc[ht], 0, 0, 0);
            }
        }
        __builtin_amdgcn_s_setprio(0);

        if (kt < NT - 1) {
            __syncthreads();
            #pragma unroll
            for (int i = 0; i < 4; i++) {
                *(bf16x8*)&Ks[srow][scb + i * 8] = kpre[i];
                *(bf16x8*)&Vs[srow][scb + i * 8] = vpre[i];
            }
            __syncthreads();
        }
    }

    // ---- merge groups: pure sums (m=0 shared reference). LDS reused as f32.
    float l_run = xswap_add(l_part);
    __syncthreads();
    float* mg = (float*)&sm[0][0][0][0];
    constexpr int SLOT = 64 * 69;
    constexpr int LBASE = 3 * SLOT;
    const int qloc = wq * 32 + l31;
    if (gk > 0) {
        float* ob = mg + (gk - 1) * SLOT + qloc * 69;
        #pragma unroll
        for (int ht = 0; ht < 2; ht++)
            #pragma unroll
            for (int r = 0; r < 16; r++)
                ob[ht * 32 + (r & 3) + 8 * (r >> 2) + 4 * h32] = oacc[ht][r];
        if (h32 == 0) mg[LBASE + (gk - 1) * 64 + qloc] = l_run;
    }
    __syncthreads();
    if (gk == 0) {
        float l_tot = l_run + mg[LBASE + qloc] + mg[LBASE + 64 + qloc] + mg[LBASE + 128 + qloc];
        float linv = 1.0f / l_tot;
        float* op = out + ((size_t)(b * NS + qt * 64 + qloc)) * NH;
        const float* o1 = mg + qloc * 69;
        #pragma unroll
        for (int ht = 0; ht < 2; ht++)
            #pragma unroll
            for (int r = 0; r < 16; r++) {
                int hv = ht * 32 + (r & 3) + 8 * (r >> 2) + 4 * h32;
                float s = oacc[ht][r] + o1[hv] + o1[SLOT + hv] + o1[2 * SLOT + hv];
                op[hv] = s * linv;
            }
    }
}

// ---------------- launcher ---------------------------------------------------
extern "C" void kernel_launch(void* const* d_in, const int* in_sizes, int n_in,
                              void* d_out, int out_size, void* d_ws, size_t ws_size,
                              hipStream_t stream)
{
    const float* x  = (const float*)d_in[0];
    const float* Wq = (const float*)d_in[1];
    const float* bq = (const float*)d_in[2];
    const float* Wk = (const float*)d_in[3];
    const float* bk = (const float*)d_in[4];
    const float* Wv = (const float*)d_in[5];
    const float* bv = (const float*)d_in[6];
    float* out = (float*)d_out;

    const size_t qkv_elems = (size_t)NB * NS * NH;   // 2,097,152
    short* Qw  = (short*)d_ws;
    short* Kw  = Qw + qkv_elems;
    short* Vwt = Kw + qkv_elems;                     // [B][64][1024]
    short* Wt  = Vwt + qkv_elems;                    // 192*768 bf16

    wtrans_kernel<<<576, 256, 0, stream>>>(Wq, Wk, Wv, Wt);
    qkv_kernel<<<(NB * NS) / 64, 256, 0, stream>>>(x, Wt, bq, bk, bv, Qw, Kw, Vwt);
    attn_kernel<<<dim3(NS / 64, NB), 512, 0, stream>>>(Qw, Kw, Vwt, out);
}